// Round 23
// baseline (107.550 us; speedup 1.0000x reference)
//
#include <hip/hip_runtime.h>

typedef __bf16 bf16x8 __attribute__((ext_vector_type(8)));
typedef float f32x4 __attribute__((ext_vector_type(4)));
typedef float f32x16 __attribute__((ext_vector_type(16)));
typedef unsigned short u16;
typedef u16 u16x8 __attribute__((ext_vector_type(8)));
typedef unsigned int u32;
typedef u32 u32x4 __attribute__((ext_vector_type(4)));
typedef unsigned long long u64;

#define DEVFN static __device__ __forceinline__

DEVFN u16 f2bf(float x) {  // RNE float->bf16 (finite inputs)
  u32 u = __builtin_bit_cast(u32, x);
  u32 r = u + 0x7FFFu + ((u >> 16) & 1u);
  return (u16)(r >> 16);
}

DEVFN float myexp2(float x) {
#if __has_builtin(__builtin_amdgcn_exp2f)
  return __builtin_amdgcn_exp2f(x);
#else
  return exp2f(x);
#endif
}

DEVFN u32 cvt_pk_bf16(float lo, float hi) {  // RNE pack: lo->[15:0], hi->[31:16]
  u32 r;
  asm("v_cvt_pk_bf16_f32 %0, %1, %2" : "=v"(r) : "v"(lo), "v"(hi));
  return r;
}

// ---------------------------------------------------------------------------
// Projection: E[b,o,f] = sum_c W[o,c] X[b,c,f] + bias[o], bf16 out.
// mat 0 (Q): transposed [b][n][f][h], scaled ALPHA*log2(e); 1 (K): same
// unscaled; 2 (V): natural [b][o][t]. 128x128 tiles, 768 blocks x 256 thr
// (4 waves x 64f x 64o, acc[4][4]) -> 1.33x fewer LDS ops per output than
// r22's 8x(32x64) (r22 accounting: LDS unit = 95% of proj wall). Staging
// keeps r22's line-economy: X as wave-wide float2 rows, W lanes along c.
// ---------------------------------------------------------------------------
__global__ __launch_bounds__(256, 3) void proj_kernel(
    const float* __restrict__ from_t, const float* __restrict__ to_t,
    const float* __restrict__ Wq, const float* __restrict__ bq,
    const float* __restrict__ Wk, const float* __restrict__ bk,
    const float* __restrict__ Wv, const float* __restrict__ bv,
    u16* __restrict__ qt, u16* __restrict__ kt, u16* __restrict__ vt) {
  const int d     = blockIdx.x;         // 768
  const int xcd   = d & 7;
  const int b     = xcd >> 1;
  const int fh    = xcd & 1;
  const int local = d >> 3;             // 0..95
  const int mat   = local >> 5;         // 0..2
  const int o0    = ((local >> 3) & 3) * 128;
  const int f0    = (fh * 8 + (local & 7)) * 128;

  const float* X    = (mat == 0) ? from_t : to_t;
  const float* W    = (mat == 0) ? Wq : (mat == 1 ? Wk : Wv);
  const float* bias = (mat == 0) ? bq : (mat == 1 ? bk : bv);
  const bool isT = (mat < 2);

  __shared__ u16 Xs[128][64];  // Xs[f][c] = X[c][f], 16B-chunk xor-swizzled
  __shared__ u16 Ws[128][64];  // Ws[o][c] = W[o][c], swizzled

  const int tid  = threadIdx.x;
  const int lane = tid & 63;
  const int w    = tid >> 6;   // 0..3

  f32x4 acc[4][4];
#pragma unroll
  for (int i = 0; i < 4; ++i)
#pragma unroll
    for (int j = 0; j < 4; ++j)
#pragma unroll
      for (int r = 0; r < 4; ++r) acc[i][j][r] = 0.f;

  const int arow0 = (w & 1) * 64;   // f-half
  const int brow0 = (w >> 1) * 64;  // o-half

  for (int c0 = 0; c0 < 512; c0 += 64) {
    __syncthreads();
    // stage X: wave w owns c rows [w*16, w*16+16); lane fp loads float2
    // along f (wave request = 512B contiguous). Packs c-pairs -> 4 b128.
    {
      const int fp = lane, cq = w;
      const float* xp =
          X + ((size_t)b * 512 + c0 + cq * 16) * 2048 + f0 + fp * 2;
      float xa[16], xb[16];
#pragma unroll
      for (int i = 0; i < 16; ++i) {
        const float2 v = *(const float2*)(xp + (size_t)i * 2048);
        xa[i] = v.x;
        xb[i] = v.y;
      }
      u32x4 pka0, pka1, pkb0, pkb1;
#pragma unroll
      for (int i = 0; i < 4; ++i) {
        pka0[i] = cvt_pk_bf16(xa[2 * i], xa[2 * i + 1]);
        pka1[i] = cvt_pk_bf16(xa[8 + 2 * i], xa[9 + 2 * i]);
        pkb0[i] = cvt_pk_bf16(xb[2 * i], xb[2 * i + 1]);
        pkb1[i] = cvt_pk_bf16(xb[8 + 2 * i], xb[9 + 2 * i]);
      }
      const int fa = fp * 2, fb = fa + 1;
      *(u32x4*)&Xs[fa][((cq * 2) ^ (fa & 7)) * 8]     = pka0;
      *(u32x4*)&Xs[fa][((cq * 2 + 1) ^ (fa & 7)) * 8] = pka1;
      *(u32x4*)&Xs[fb][((cq * 2) ^ (fb & 7)) * 8]     = pkb0;
      *(u32x4*)&Xs[fb][((cq * 2 + 1) ^ (fb & 7)) * 8] = pkb1;
    }
    // stage W: 1024 tasks (128 o x 8 cg), lanes along c -> 2 lines/o-row
#pragma unroll
    for (int i = 0; i < 4; ++i) {
      const int task = tid + 256 * i;
      const int o = task >> 3, cg = task & 7;
      const float* wp = W + (size_t)(o0 + o) * 512 + c0 + cg * 8;
      const float4 w0 = *(const float4*)(wp);
      const float4 w1 = *(const float4*)(wp + 4);
      u32x4 pk;
      pk[0] = cvt_pk_bf16(w0.x, w0.y);
      pk[1] = cvt_pk_bf16(w0.z, w0.w);
      pk[2] = cvt_pk_bf16(w1.x, w1.y);
      pk[3] = cvt_pk_bf16(w1.z, w1.w);
      *(u32x4*)&Ws[o][(cg ^ (o & 7)) * 8] = pk;
    }
    __syncthreads();

#pragma unroll
    for (int kk = 0; kk < 2; ++kk) {
      const int cb8 = kk * 4;
      bf16x8 afr[4], bfr[4];
#pragma unroll
      for (int mi = 0; mi < 4; ++mi) {
        const int row = arow0 + mi * 16 + (lane & 15);
        const int ch  = (cb8 + (lane >> 4)) ^ (row & 7);
        afr[mi] = *(const bf16x8*)&(isT ? Xs : Ws)[row][ch * 8];
      }
#pragma unroll
      for (int ni = 0; ni < 4; ++ni) {
        const int row = brow0 + ni * 16 + (lane & 15);
        const int ch  = (cb8 + (lane >> 4)) ^ (row & 7);
        bfr[ni] = *(const bf16x8*)&(isT ? Ws : Xs)[row][ch * 8];
      }
#pragma unroll
      for (int mi = 0; mi < 4; ++mi)
#pragma unroll
        for (int ni = 0; ni < 4; ++ni)
          acc[mi][ni] = __builtin_amdgcn_mfma_f32_16x16x32_bf16(
              afr[mi], bfr[ni], acc[mi][ni], 0, 0, 0);
    }
  }

  const float qscale = 0.18033688011112042f;  // (1/8) * log2(e)
#pragma unroll
  for (int mi = 0; mi < 4; ++mi)
#pragma unroll
    for (int ni = 0; ni < 4; ++ni)
#pragma unroll
      for (int r = 0; r < 4; ++r) {
        const int rA = arow0 + mi * 16 + (lane >> 4) * 4 + r;
        const int cB = brow0 + ni * 16 + (lane & 15);
        int f, o;
        if (isT) { f = f0 + rA; o = o0 + cB; }
        else     { o = o0 + rA; f = f0 + cB; }
        float val = acc[mi][ni][r] + bias[o];
        if (mat == 0) val *= qscale;
        const u16 hv = f2bf(val);
        if (isT) {
          u16* dst = (mat == 0) ? qt : kt;
          dst[(((size_t)b * 8 + (o >> 6)) * 2048 + f) * 64 + (o & 63)] = hv;
        } else {
          vt[((size_t)b * 512 + o) * 2048 + f] = hv;
        }
      }
}

// ---------------------------------------------------------------------------
// Mask uniformity pre-pass: bit `tile` of fmask[b*16+ft] = (all of
// mask[b][ft*128..+128)[tile*64..+64) == 1.0f). fmask must be zeroed first.
// ---------------------------------------------------------------------------
__global__ __launch_bounds__(256, 4) void maskflag_kernel(
    const float* __restrict__ mask, u32* __restrict__ fmask) {
  const int d    = blockIdx.x;      // [b][ft][tile] = 4*16*32
  const int b    = d >> 9;
  const int ft   = (d >> 5) & 15;
  const int tile = d & 31;
  const int t    = threadIdx.x;

  const float* base =
      mask + ((size_t)b * 2048 + ft * 128) * 2048 + tile * 64;
  bool ok = true;
#pragma unroll
  for (int i = 0; i < 8; ++i) {
    const int row = (t >> 4) * 8 + i;
    const float4 v = *(const float4*)(base + (size_t)row * 2048 + (t & 15) * 4);
    ok = ok && (v.x == 1.0f) && (v.y == 1.0f) && (v.z == 1.0f) && (v.w == 1.0f);
  }
  const u64 bal = __ballot(ok);
  __shared__ u32 wok[4];
  if ((t & 63) == 0) wok[t >> 6] = (bal == ~0ull) ? 1u : 0u;
  __syncthreads();
  if (t == 0) {
    const u32 allok = wok[0] & wok[1] & wok[2] & wok[3];
    if (allok) atomicOr(&fmask[b * 16 + ft], 1u << tile);
  }
}

// ---------------------------------------------------------------------------
// Attention: 512 blocks x 256 thr (4 waves x 32 q-rows), KVBLK=64.
// 4-buffer LDS rotation -> ONE barrier + one vmcnt(0) per round (stage of
// tile r+2 goes to buf[(r+2)&3], disjoint from this round's read bufs).
// Compiler-managed lgkmcnt. Uniform-mask fast path: one scalar fmask word
// per block, per-round SALU bit test skips 8 mask loads + 32 fma (bias==0
// exactly). General-mask slow path preserved. Fixed-M softmax; r9-verified
// permlane P-exchange. Pipeline: round r does QK_{r+1} || softmax_r -> PV_r.
// ---------------------------------------------------------------------------
#define SB __builtin_amdgcn_sched_barrier(0)

#define STAGE(BB, T0)                                                          \
  do {                                                                         \
    __builtin_amdgcn_global_load_lds(                                          \
        (const __attribute__((address_space(1))) void*)(ksrc1 + (size_t)(T0) * 64), \
        (__attribute__((address_space(3))) void*)&Ks[BB][w * 16][0], 16, 0, 0);\
    __builtin_amdgcn_global_load_lds(                                          \
        (const __attribute__((address_space(1))) void*)(ksrc2 + (size_t)(T0) * 64), \
        (__attribute__((address_space(3))) void*)&Ks[BB][w * 16 + 8][0], 16, 0, 0); \
    __builtin_amdgcn_global_load_lds(                                          \
        (const __attribute__((address_space(1))) void*)(vsrc1 + (T0)),         \
        (__attribute__((address_space(3))) void*)&Vs[BB][w * 16][0], 16, 0, 0);\
    __builtin_amdgcn_global_load_lds(                                          \
        (const __attribute__((address_space(1))) void*)(vsrc2 + (T0)),         \
        (__attribute__((address_space(3))) void*)&Vs[BB][w * 16 + 8][0], 16, 0, 0); \
  } while (0)

#define LDK(BUF)                                                               \
  do {                                                                         \
    _Pragma("unroll")                                                          \
    for (int kf_ = 0; kf_ < 4; ++kf_)                                          \
      _Pragma("unroll")                                                        \
      for (int mi_ = 0; mi_ < 2; ++mi_) {                                      \
        const int row_ = mi_ * 32 + fl;                                        \
        kreg[mi_][kf_] =                                                       \
            *(const bf16x8*)&Ks[BUF][row_][((kf_ * 2 + g) ^ (row_ & 7)) * 8];  \
      }                                                                        \
  } while (0)

#define LDV(BUF)                                                               \
  do {                                                                         \
    _Pragma("unroll")                                                          \
    for (int tf_ = 0; tf_ < 4; ++tf_)                                          \
      _Pragma("unroll")                                                        \
      for (int mh_ = 0; mh_ < 2; ++mh_) {                                      \
        const int row_ = mh_ * 32 + fl;                                        \
        vreg[mh_][tf_] =                                                       \
            *(const bf16x8*)&Vs[BUF][row_][((tf_ * 2 + g) ^ (row_ & 7)) * 8];  \
      }                                                                        \
  } while (0)

// QK into SN (C=0), from kreg
#define QKMM(SN)                                                               \
  do {                                                                         \
    _Pragma("unroll")                                                          \
    for (int m_ = 0; m_ < 2; ++m_)                                             \
      _Pragma("unroll")                                                        \
      for (int r_ = 0; r_ < 16; ++r_) SN[m_][r_] = 0.f;                        \
    _Pragma("unroll")                                                          \
    for (int kf_ = 0; kf_ < 4; ++kf_)                                          \
      _Pragma("unroll")                                                        \
      for (int mi_ = 0; mi_ < 2; ++mi_)                                        \
        SN[mi_] = __builtin_amdgcn_mfma_f32_32x32x16_bf16(kreg[mi_][kf_],      \
                                                          qf[kf_], SN[mi_],    \
                                                          0, 0, 0);            \
  } while (0)

// Round r: RB = r&3; SC current scores (consumed), SN next (produced); T0=r*64
#define ROUND(RB, SC, SN, T0)                                                  \
  {                                                                            \
    asm volatile("s_waitcnt vmcnt(0)" ::: "memory");                           \
    SB;                                                                        \
    __builtin_amdgcn_s_barrier();                                              \
    SB;                                                                        \
    LDV(RB);                                                                   \
    LDK((RB + 1) & 3);                                                         \
    SB;                                                                        \
    STAGE((RB + 2) & 3, ((T0) + 128) & 2047);                                  \
    SB;                                                                        \
    QKMM(SN); /* QK_{r+1}, independent of softmax_r -> interleaves */          \
    /* softmax_r: mask bias (slow path only) then fixed-M exp2 */              \
    if (!((fmask >> ((T0) >> 6)) & 1u)) {                                      \
      float4 mk[8];                                                            \
      _Pragma("unroll")                                                        \
      for (int i_ = 0; i_ < 8; ++i_)                                           \
        mk[i_] = *(const float4*)(mrow + (T0) + (i_ >> 2) * 32 +               \
                                  (i_ & 3) * 8 + g * 4);                       \
      _Pragma("unroll")                                                        \
      for (int mi = 0; mi < 2; ++mi)                                           \
        _Pragma("unroll")                                                      \
        for (int q = 0; q < 4; ++q) {                                          \
          const float4 mv = mk[mi * 4 + q];                                    \
          SC[mi][q * 4 + 0] = fmaf(mv.x - 1.f, 144269.50408889634f, SC[mi][q * 4 + 0]); \
          SC[mi][q * 4 + 1] = fmaf(mv.y - 1.f, 144269.50408889634f, SC[mi][q * 4 + 1]); \
          SC[mi][q * 4 + 2] = fmaf(mv.z - 1.f, 144269.50408889634f, SC[mi][q * 4 + 2]); \
          SC[mi][q * 4 + 3] = fmaf(mv.w - 1.f, 144269.50408889634f, SC[mi][q * 4 + 3]); \
        }                                                                      \
    }                                                                          \
    float ps0 = 0.f, ps1 = 0.f, ps2 = 0.f, ps3 = 0.f;                          \
    _Pragma("unroll")                                                          \
    for (int mi = 0; mi < 2; ++mi)                                             \
      _Pragma("unroll")                                                        \
      for (int r = 0; r < 16; r += 4) {                                        \
        SC[mi][r + 0] = myexp2(SC[mi][r + 0]); ps0 += SC[mi][r + 0];           \
        SC[mi][r + 1] = myexp2(SC[mi][r + 1]); ps1 += SC[mi][r + 1];           \
        SC[mi][r + 2] = myexp2(SC[mi][r + 2]); ps2 += SC[mi][r + 2];           \
        SC[mi][r + 3] = myexp2(SC[mi][r + 3]); ps3 += SC[mi][r + 3];           \
      }                                                                        \
    {                                                                          \
      float ps = (ps0 + ps1) + (ps2 + ps3);                                    \
      ps += __shfl_xor(ps, 32, 64);                                            \
      L += ps;                                                                 \
    }                                                                          \
    /* pack P -> bf16 dwords; exchange halves via v_permlane32_swap (r9) */    \
    u32 dwv[2][4][2];                                                          \
    _Pragma("unroll")                                                          \
    for (int mi = 0; mi < 2; ++mi)                                             \
      _Pragma("unroll")                                                        \
      for (int q = 0; q < 4; ++q) {                                            \
        dwv[mi][q][0] = cvt_pk_bf16(SC[mi][q * 4 + 0], SC[mi][q * 4 + 1]);     \
        dwv[mi][q][1] = cvt_pk_bf16(SC[mi][q * 4 + 2], SC[mi][q * 4 + 3]);     \
      }                                                                        \
    _Pragma("unroll")                                                          \
    for (int tf = 0; tf < 4; ++tf) {                                           \
      const int m_ = tf >> 1, bq2 = tf & 1;                                    \
      u32 A0 = dwv[m_][bq2 * 2][0], A1 = dwv[m_][bq2 * 2][1];                  \
      u32 C0 = dwv[m_][bq2 * 2 + 1][0], C1 = dwv[m_][bq2 * 2 + 1][1];          \
      asm("v_permlane32_swap_b32 %0, %1" : "+v"(A0), "+v"(C0));                \
      asm("v_permlane32_swap_b32 %0, %1" : "+v"(A1), "+v"(C1));                \
      u32x4 pw; pw[0] = A0; pw[1] = A1; pw[2] = C0; pw[3] = C1;                \
      const bf16x8 pfr = __builtin_bit_cast(bf16x8, pw);                       \
      _Pragma("unroll")                                                        \
      for (int mih = 0; mih < 2; ++mih)                                        \
        ctx[mih] = __builtin_amdgcn_mfma_f32_32x32x16_bf16(vreg[mih][tf], pfr, \
                                                           ctx[mih], 0, 0, 0); \
    }                                                                          \
  }

__global__ __launch_bounds__(256, 2) void attn_kernel(
    const float* __restrict__ mask, const u32* __restrict__ fmaskbuf,
    const u16* __restrict__ qt, const u16* __restrict__ kt,
    const u16* __restrict__ vt, float* __restrict__ out) {
  const int d     = blockIdx.x;   // 512; xcd = d&7 (HW round-robin)
  const int xcd   = d & 7;
  const int b     = xcd >> 1;
  const int fthi  = xcd & 1;
  const int local = d >> 3;       // 0..63
  const int n     = local & 7;
  const int ft    = fthi * 8 + (local >> 3);

  const int tid  = threadIdx.x;
  const int lane = tid & 63;
  const int w    = tid >> 6;      // 0..3
  const int g    = lane >> 5;
  const int fl   = lane & 31;
  const int f    = ft * 128 + w * 32 + fl;

  const u16* qtb = qt + ((size_t)b * 8 + n) * 2048 * 64;
  const u16* ktb = kt + ((size_t)b * 8 + n) * 2048 * 64;
  const u16* vb  = vt + ((size_t)b * 512 + n * 64) * 2048;
  const float* mrow = mask + ((size_t)b * 2048 + f) * 2048;
  const u32 fmask = fmaskbuf ? fmaskbuf[b * 16 + ft] : 0u;

  __shared__ u16 Ks[4][64][64];  // [t][h], chunk-swizzled, 4-buffer rotation
  __shared__ u16 Vs[4][64][64];  // [h][t], chunk-swizzled

  bf16x8 qf[4];
#pragma unroll
  for (int kf = 0; kf < 4; ++kf)
    qf[kf] = *(const bf16x8*)(qtb + (size_t)f * 64 + kf * 16 + g * 8);

  f32x16 ctx[2];
#pragma unroll
  for (int m = 0; m < 2; ++m)
#pragma unroll
    for (int r = 0; r < 16; ++r) ctx[m][r] = 0.f;
  float L = 0.f;

  // staging geometry: wave w owns rows w*16..w*16+15 (2 gload_lds per tensor)
  const int sr1 = w * 16 + (lane >> 3), sr2 = sr1 + 8;
  const int sc1 = (lane & 7) ^ (sr1 & 7), sc2 = (lane & 7) ^ (sr2 & 7);
  const u16* ksrc1 = ktb + (size_t)sr1 * 64 + sc1 * 8;
  const u16* ksrc2 = ktb + (size_t)sr2 * 64 + sc2 * 8;
  const u16* vsrc1 = vb + (size_t)sr1 * 2048 + sc1 * 8;
  const u16* vsrc2 = vb + (size_t)sr2 * 2048 + sc2 * 8;

  bf16x8 kreg[2][4], vreg[2][4];
  f32x16 sA[2], sB[2];

  // ---- prologue: stage tiles 0,1; compute QK_0 into sA ----
  STAGE(0, 0);
  STAGE(1, 64);
  SB;
  asm volatile("s_waitcnt vmcnt(0)" ::: "memory");
  SB;
  __builtin_amdgcn_s_barrier();
  SB;
  LDK(0);
  QKMM(sA);  // s_0 (compiler inserts precise lgkm waits)

  for (int t0 = 0; t0 < 2048; t0 += 256) {
    ROUND(0, sA, sB, t0);
    ROUND(1, sB, sA, t0 + 64);
    ROUND(2, sA, sB, t0 + 128);
    ROUND(3, sB, sA, t0 + 192);
  }

  const float Linv = 1.0f / L;
#pragma unroll
  for (int mih = 0; mih < 2; ++mih)
#pragma unroll
    for (int r = 0; r < 16; ++r) {
      const int h = mih * 32 + (r & 3) + 8 * (r >> 2) + 4 * g;
      out[((size_t)b * 512 + n * 64 + h) * 2048 + f] = ctx[mih][r] * Linv;
    }
}

extern "C" void kernel_launch(void* const* d_in, const int* in_sizes, int n_in,
                              void* d_out, int out_size, void* d_ws, size_t ws_size,
                              hipStream_t stream) {
  const float* from_t = (const float*)d_in[0];
  const float* to_t   = (const float*)d_in[1];
  const float* mask   = (const float*)d_in[2];
  const float* Wq     = (const float*)d_in[3];
  const float* bq     = (const float*)d_in[4];
  const float* Wk     = (const float*)d_in[5];
  const float* bk     = (const float*)d_in[6];
  const float* Wv     = (const float*)d_in[7];
  const float* bv     = (const float*)d_in[8];
  float* out = (float*)d_out;

  u16* qt = (u16*)d_ws;                        // [4][8][2048][64] bf16 = 8MB
  u16* kt = qt + (size_t)4 * 8 * 2048 * 64;    // 8MB
  u16* vt = kt + (size_t)4 * 8 * 2048 * 64;    // [4][512][2048] bf16 = 8MB
  const size_t base = (size_t)24 * 1024 * 1024;
  u32* fl = (ws_size >= base + 256) ? (u32*)((char*)d_ws + base) : nullptr;

  proj_kernel<<<dim3(768), 256, 0, stream>>>(from_t, to_t, Wq, bq, Wk, bk,
                                             Wv, bv, qt, kt, vt);
  if (fl) {
    (void)hipMemsetAsync(fl, 0, 64 * sizeof(u32), stream);
    maskflag_kernel<<<dim3(2048), 256, 0, stream>>>(mask, fl);
  }
  attn_kernel<<<dim3(512), 256, 0, stream>>>(mask, fl, qt, kt, vt, out);
}

// Round 24
// 100.611 us; speedup vs baseline: 1.0690x; 1.0690x over previous
//
#include <hip/hip_runtime.h>

typedef __bf16 bf16x8 __attribute__((ext_vector_type(8)));
typedef float f32x4 __attribute__((ext_vector_type(4)));
typedef float f32x16 __attribute__((ext_vector_type(16)));
typedef unsigned short u16;
typedef u16 u16x8 __attribute__((ext_vector_type(8)));
typedef unsigned int u32;
typedef u32 u32x4 __attribute__((ext_vector_type(4)));
typedef unsigned long long u64;

#define DEVFN static __device__ __forceinline__

DEVFN u16 f2bf(float x) {  // RNE float->bf16 (finite inputs)
  u32 u = __builtin_bit_cast(u32, x);
  u32 r = u + 0x7FFFu + ((u >> 16) & 1u);
  return (u16)(r >> 16);
}

DEVFN float myexp2(float x) {
#if __has_builtin(__builtin_amdgcn_exp2f)
  return __builtin_amdgcn_exp2f(x);
#else
  return exp2f(x);
#endif
}

DEVFN u32 cvt_pk_bf16(float lo, float hi) {  // RNE pack: lo->[15:0], hi->[31:16]
  u32 r;
  asm("v_cvt_pk_bf16_f32 %0, %1, %2" : "=v"(r) : "v"(lo), "v"(hi));
  return r;
}

// ---------------------------------------------------------------------------
// Projection: E[b,o,f] = sum_c W[o,c] X[b,c,f] + bias[o], bf16 out.
// mat 0 (Q): transposed [b][n][f][h], scaled ALPHA*log2(e); 1 (K): same
// unscaled; 2 (V): natural [b][o][t]. 128x128 tiles, 768 blocks x 512 thr
// (8 waves, 32f x 64o each). r22 staging (L1-line economy): W lanes along c
// (8 lines/request vs 64), X as float2-along-f (8 wide requests vs 16
// scalar). Measured best: 49 us (r22). r23's 4-wave acc[4][4] variant
// regressed to 56 us (occupancy loss > LDS-op gain) - reverted.
// ---------------------------------------------------------------------------
__global__ __launch_bounds__(512, 6) void proj_kernel(
    const float* __restrict__ from_t, const float* __restrict__ to_t,
    const float* __restrict__ Wq, const float* __restrict__ bq,
    const float* __restrict__ Wk, const float* __restrict__ bk,
    const float* __restrict__ Wv, const float* __restrict__ bv,
    u16* __restrict__ qt, u16* __restrict__ kt, u16* __restrict__ vt) {
  const int d     = blockIdx.x;         // 768
  const int xcd   = d & 7;
  const int b     = xcd >> 1;
  const int fh    = xcd & 1;
  const int local = d >> 3;             // 0..95
  const int mat   = local >> 5;         // 0..2
  const int o0    = ((local >> 3) & 3) * 128;
  const int f0    = (fh * 8 + (local & 7)) * 128;

  const float* X    = (mat == 0) ? from_t : to_t;
  const float* W    = (mat == 0) ? Wq : (mat == 1 ? Wk : Wv);
  const float* bias = (mat == 0) ? bq : (mat == 1 ? bk : bv);
  const bool isT = (mat < 2);

  __shared__ u16 Xs[128][64];  // Xs[f][c] = X[c][f], 16B-chunk xor-swizzled
  __shared__ u16 Ws[128][64];  // Ws[o][c] = W[o][c], swizzled

  const int tid  = threadIdx.x;
  const int lane = tid & 63;
  const int w    = tid >> 6;   // 0..7

  f32x4 acc[2][4];
#pragma unroll
  for (int i = 0; i < 2; ++i)
#pragma unroll
    for (int j = 0; j < 4; ++j)
#pragma unroll
      for (int r = 0; r < 4; ++r) acc[i][j][r] = 0.f;

  const int arow0 = (w & 3) * 32;   // f-quarter (32 rows)
  const int brow0 = (w >> 2) * 64;  // o-half    (64 rows)

  for (int c0 = 0; c0 < 512; c0 += 64) {
    __syncthreads();
    // stage X: thread = (cg 0..7, fp 0..63); 8 float2 along f (contiguous
    // 512B per wave-request), writes 2 LDS rows with the proven b128 pattern
    {
      const int fp = tid & 63, cg = tid >> 6;
      const float* xp =
          X + ((size_t)b * 512 + c0 + cg * 8) * 2048 + f0 + fp * 2;
      float xa[8], xb[8];
#pragma unroll
      for (int i = 0; i < 8; ++i) {
        const float2 v = *(const float2*)(xp + (size_t)i * 2048);
        xa[i] = v.x;
        xb[i] = v.y;
      }
      u32x4 pka, pkb;
#pragma unroll
      for (int i = 0; i < 4; ++i) {
        pka[i] = cvt_pk_bf16(xa[2 * i], xa[2 * i + 1]);
        pkb[i] = cvt_pk_bf16(xb[2 * i], xb[2 * i + 1]);
      }
      const int fa = fp * 2, fb = fa + 1;
      *(u32x4*)&Xs[fa][(cg ^ (fa & 7)) * 8] = pka;
      *(u32x4*)&Xs[fb][(cg ^ (fb & 7)) * 8] = pkb;
    }
    // stage W: 1024 tasks (128 o x 8 cg), lanes along c -> 8 lines/request
#pragma unroll
    for (int i = 0; i < 2; ++i) {
      const int task = tid + 512 * i;
      const int o = task >> 3, cg = task & 7;
      const float* wp = W + (size_t)(o0 + o) * 512 + c0 + cg * 8;
      const float4 w0 = *(const float4*)(wp);
      const float4 w1 = *(const float4*)(wp + 4);
      u32x4 pk;
      pk[0] = cvt_pk_bf16(w0.x, w0.y);
      pk[1] = cvt_pk_bf16(w0.z, w0.w);
      pk[2] = cvt_pk_bf16(w1.x, w1.y);
      pk[3] = cvt_pk_bf16(w1.z, w1.w);
      *(u32x4*)&Ws[o][(cg ^ (o & 7)) * 8] = pk;
    }
    __syncthreads();

#pragma unroll
    for (int kk = 0; kk < 2; ++kk) {
      const int cb8 = kk * 4;
      bf16x8 afr[2], bfr[4];
#pragma unroll
      for (int mi = 0; mi < 2; ++mi) {
        const int row = arow0 + mi * 16 + (lane & 15);
        const int ch  = (cb8 + (lane >> 4)) ^ (row & 7);
        afr[mi] = *(const bf16x8*)&(isT ? Xs : Ws)[row][ch * 8];
      }
#pragma unroll
      for (int ni = 0; ni < 4; ++ni) {
        const int row = brow0 + ni * 16 + (lane & 15);
        const int ch  = (cb8 + (lane >> 4)) ^ (row & 7);
        bfr[ni] = *(const bf16x8*)&(isT ? Ws : Xs)[row][ch * 8];
      }
#pragma unroll
      for (int mi = 0; mi < 2; ++mi)
#pragma unroll
        for (int ni = 0; ni < 4; ++ni)
          acc[mi][ni] = __builtin_amdgcn_mfma_f32_16x16x32_bf16(
              afr[mi], bfr[ni], acc[mi][ni], 0, 0, 0);
    }
  }

  const float qscale = 0.18033688011112042f;  // (1/8) * log2(e)
#pragma unroll
  for (int mi = 0; mi < 2; ++mi)
#pragma unroll
    for (int ni = 0; ni < 4; ++ni)
#pragma unroll
      for (int r = 0; r < 4; ++r) {
        const int rA = arow0 + mi * 16 + (lane >> 4) * 4 + r;
        const int cB = brow0 + ni * 16 + (lane & 15);
        int f, o;
        if (isT) { f = f0 + rA; o = o0 + cB; }
        else     { o = o0 + rA; f = f0 + cB; }
        float val = acc[mi][ni][r] + bias[o];
        if (mat == 0) val *= qscale;
        const u16 hv = f2bf(val);
        if (isT) {
          u16* dst = (mat == 0) ? qt : kt;
          dst[(((size_t)b * 8 + (o >> 6)) * 2048 + f) * 64 + (o & 63)] = hv;
        } else {
          vt[((size_t)b * 512 + o) * 2048 + f] = hv;
        }
      }
}

// ---------------------------------------------------------------------------
// Mask uniformity pre-pass: bit `tile` of fmask[b*16+ft] = (all of
// mask[b][ft*128..+128)[tile*64..+64) == 1.0f). fmask must be zeroed first.
// ---------------------------------------------------------------------------
__global__ __launch_bounds__(256, 4) void maskflag_kernel(
    const float* __restrict__ mask, u32* __restrict__ fmask) {
  const int d    = blockIdx.x;      // [b][ft][tile] = 4*16*32
  const int b    = d >> 9;
  const int ft   = (d >> 5) & 15;
  const int tile = d & 31;
  const int t    = threadIdx.x;

  const float* base =
      mask + ((size_t)b * 2048 + ft * 128) * 2048 + tile * 64;
  bool ok = true;
#pragma unroll
  for (int i = 0; i < 8; ++i) {
    const int row = (t >> 4) * 8 + i;
    const float4 v = *(const float4*)(base + (size_t)row * 2048 + (t & 15) * 4);
    ok = ok && (v.x == 1.0f) && (v.y == 1.0f) && (v.z == 1.0f) && (v.w == 1.0f);
  }
  const u64 bal = __ballot(ok);
  __shared__ u32 wok[4];
  if ((t & 63) == 0) wok[t >> 6] = (bal == ~0ull) ? 1u : 0u;
  __syncthreads();
  if (t == 0) {
    const u32 allok = wok[0] & wok[1] & wok[2] & wok[3];
    if (allok) atomicOr(&fmask[b * 16 + ft], 1u << tile);
  }
}

// ---------------------------------------------------------------------------
// Attention: 512 blocks x 256 thr (4 waves x 32 q-rows), KVBLK=64.
// 4-buffer LDS rotation -> ONE barrier + one vmcnt(0) per round (stage of
// tile r+2 goes to buf[(r+2)&3], disjoint from this round's read bufs).
// Compiler-managed lgkmcnt. Uniform-mask fast path: one scalar fmask word
// per block, per-round SALU bit test skips 8 mask loads + 32 fma (bias==0
// exactly). General-mask slow path preserved. Fixed-M softmax; r9-verified
// permlane P-exchange. Pipeline: round r does QK_{r+1} || softmax_r -> PV_r.
// ---------------------------------------------------------------------------
#define SB __builtin_amdgcn_sched_barrier(0)

#define STAGE(BB, T0)                                                          \
  do {                                                                         \
    __builtin_amdgcn_global_load_lds(                                          \
        (const __attribute__((address_space(1))) void*)(ksrc1 + (size_t)(T0) * 64), \
        (__attribute__((address_space(3))) void*)&Ks[BB][w * 16][0], 16, 0, 0);\
    __builtin_amdgcn_global_load_lds(                                          \
        (const __attribute__((address_space(1))) void*)(ksrc2 + (size_t)(T0) * 64), \
        (__attribute__((address_space(3))) void*)&Ks[BB][w * 16 + 8][0], 16, 0, 0); \
    __builtin_amdgcn_global_load_lds(                                          \
        (const __attribute__((address_space(1))) void*)(vsrc1 + (T0)),         \
        (__attribute__((address_space(3))) void*)&Vs[BB][w * 16][0], 16, 0, 0);\
    __builtin_amdgcn_global_load_lds(                                          \
        (const __attribute__((address_space(1))) void*)(vsrc2 + (T0)),         \
        (__attribute__((address_space(3))) void*)&Vs[BB][w * 16 + 8][0], 16, 0, 0); \
  } while (0)

#define LDK(BUF)                                                               \
  do {                                                                         \
    _Pragma("unroll")                                                          \
    for (int kf_ = 0; kf_ < 4; ++kf_)                                          \
      _Pragma("unroll")                                                        \
      for (int mi_ = 0; mi_ < 2; ++mi_) {                                      \
        const int row_ = mi_ * 32 + fl;                                        \
        kreg[mi_][kf_] =                                                       \
            *(const bf16x8*)&Ks[BUF][row_][((kf_ * 2 + g) ^ (row_ & 7)) * 8];  \
      }                                                                        \
  } while (0)

#define LDV(BUF)                                                               \
  do {                                                                         \
    _Pragma("unroll")                                                          \
    for (int tf_ = 0; tf_ < 4; ++tf_)                                          \
      _Pragma("unroll")                                                        \
      for (int mh_ = 0; mh_ < 2; ++mh_) {                                      \
        const int row_ = mh_ * 32 + fl;                                        \
        vreg[mh_][tf_] =                                                       \
            *(const bf16x8*)&Vs[BUF][row_][((tf_ * 2 + g) ^ (row_ & 7)) * 8];  \
      }                                                                        \
  } while (0)

// QK into SN (C=0), from kreg
#define QKMM(SN)                                                               \
  do {                                                                         \
    _Pragma("unroll")                                                          \
    for (int m_ = 0; m_ < 2; ++m_)                                             \
      _Pragma("unroll")                                                        \
      for (int r_ = 0; r_ < 16; ++r_) SN[m_][r_] = 0.f;                        \
    _Pragma("unroll")                                                          \
    for (int kf_ = 0; kf_ < 4; ++kf_)                                          \
      _Pragma("unroll")                                                        \
      for (int mi_ = 0; mi_ < 2; ++mi_)                                        \
        SN[mi_] = __builtin_amdgcn_mfma_f32_32x32x16_bf16(kreg[mi_][kf_],      \
                                                          qf[kf_], SN[mi_],    \
                                                          0, 0, 0);            \
  } while (0)

// Round r: RB = r&3; SC current scores (consumed), SN next (produced); T0=r*64
#define ROUND(RB, SC, SN, T0)                                                  \
  {                                                                            \
    asm volatile("s_waitcnt vmcnt(0)" ::: "memory");                           \
    SB;                                                                        \
    __builtin_amdgcn_s_barrier();                                              \
    SB;                                                                        \
    LDV(RB);                                                                   \
    LDK((RB + 1) & 3);                                                         \
    SB;                                                                        \
    STAGE((RB + 2) & 3, ((T0) + 128) & 2047);                                  \
    SB;                                                                        \
    QKMM(SN); /* QK_{r+1}, independent of softmax_r -> interleaves */          \
    /* softmax_r: mask bias (slow path only) then fixed-M exp2 */              \
    if (!((fmask >> ((T0) >> 6)) & 1u)) {                                      \
      float4 mk[8];                                                            \
      _Pragma("unroll")                                                        \
      for (int i_ = 0; i_ < 8; ++i_)                                           \
        mk[i_] = *(const float4*)(mrow + (T0) + (i_ >> 2) * 32 +               \
                                  (i_ & 3) * 8 + g * 4);                       \
      _Pragma("unroll")                                                        \
      for (int mi = 0; mi < 2; ++mi)                                           \
        _Pragma("unroll")                                                      \
        for (int q = 0; q < 4; ++q) {                                          \
          const float4 mv = mk[mi * 4 + q];                                    \
          SC[mi][q * 4 + 0] = fmaf(mv.x - 1.f, 144269.50408889634f, SC[mi][q * 4 + 0]); \
          SC[mi][q * 4 + 1] = fmaf(mv.y - 1.f, 144269.50408889634f, SC[mi][q * 4 + 1]); \
          SC[mi][q * 4 + 2] = fmaf(mv.z - 1.f, 144269.50408889634f, SC[mi][q * 4 + 2]); \
          SC[mi][q * 4 + 3] = fmaf(mv.w - 1.f, 144269.50408889634f, SC[mi][q * 4 + 3]); \
        }                                                                      \
    }                                                                          \
    float ps0 = 0.f, ps1 = 0.f, ps2 = 0.f, ps3 = 0.f;                          \
    _Pragma("unroll")                                                          \
    for (int mi = 0; mi < 2; ++mi)                                             \
      _Pragma("unroll")                                                        \
      for (int r = 0; r < 16; r += 4) {                                        \
        SC[mi][r + 0] = myexp2(SC[mi][r + 0]); ps0 += SC[mi][r + 0];           \
        SC[mi][r + 1] = myexp2(SC[mi][r + 1]); ps1 += SC[mi][r + 1];           \
        SC[mi][r + 2] = myexp2(SC[mi][r + 2]); ps2 += SC[mi][r + 2];           \
        SC[mi][r + 3] = myexp2(SC[mi][r + 3]); ps3 += SC[mi][r + 3];           \
      }                                                                        \
    {                                                                          \
      float ps = (ps0 + ps1) + (ps2 + ps3);                                    \
      ps += __shfl_xor(ps, 32, 64);                                            \
      L += ps;                                                                 \
    }                                                                          \
    /* pack P -> bf16 dwords; exchange halves via v_permlane32_swap (r9) */    \
    u32 dwv[2][4][2];                                                          \
    _Pragma("unroll")                                                          \
    for (int mi = 0; mi < 2; ++mi)                                             \
      _Pragma("unroll")                                                        \
      for (int q = 0; q < 4; ++q) {                                            \
        dwv[mi][q][0] = cvt_pk_bf16(SC[mi][q * 4 + 0], SC[mi][q * 4 + 1]);     \
        dwv[mi][q][1] = cvt_pk_bf16(SC[mi][q * 4 + 2], SC[mi][q * 4 + 3]);     \
      }                                                                        \
    _Pragma("unroll")                                                          \
    for (int tf = 0; tf < 4; ++tf) {                                           \
      const int m_ = tf >> 1, bq2 = tf & 1;                                    \
      u32 A0 = dwv[m_][bq2 * 2][0], A1 = dwv[m_][bq2 * 2][1];                  \
      u32 C0 = dwv[m_][bq2 * 2 + 1][0], C1 = dwv[m_][bq2 * 2 + 1][1];          \
      asm("v_permlane32_swap_b32 %0, %1" : "+v"(A0), "+v"(C0));                \
      asm("v_permlane32_swap_b32 %0, %1" : "+v"(A1), "+v"(C1));                \
      u32x4 pw; pw[0] = A0; pw[1] = A1; pw[2] = C0; pw[3] = C1;                \
      const bf16x8 pfr = __builtin_bit_cast(bf16x8, pw);                       \
      _Pragma("unroll")                                                        \
      for (int mih = 0; mih < 2; ++mih)                                        \
        ctx[mih] = __builtin_amdgcn_mfma_f32_32x32x16_bf16(vreg[mih][tf], pfr, \
                                                           ctx[mih], 0, 0, 0); \
    }                                                                          \
  }

__global__ __launch_bounds__(256, 2) void attn_kernel(
    const float* __restrict__ mask, const u32* __restrict__ fmaskbuf,
    const u16* __restrict__ qt, const u16* __restrict__ kt,
    const u16* __restrict__ vt, float* __restrict__ out) {
  const int d     = blockIdx.x;   // 512; xcd = d&7 (HW round-robin)
  const int xcd   = d & 7;
  const int b     = xcd >> 1;
  const int fthi  = xcd & 1;
  const int local = d >> 3;       // 0..63
  const int n     = local & 7;
  const int ft    = fthi * 8 + (local >> 3);

  const int tid  = threadIdx.x;
  const int lane = tid & 63;
  const int w    = tid >> 6;      // 0..3
  const int g    = lane >> 5;
  const int fl   = lane & 31;
  const int f    = ft * 128 + w * 32 + fl;

  const u16* qtb = qt + ((size_t)b * 8 + n) * 2048 * 64;
  const u16* ktb = kt + ((size_t)b * 8 + n) * 2048 * 64;
  const u16* vb  = vt + ((size_t)b * 512 + n * 64) * 2048;
  const float* mrow = mask + ((size_t)b * 2048 + f) * 2048;
  const u32 fmask = fmaskbuf ? fmaskbuf[b * 16 + ft] : 0u;

  __shared__ u16 Ks[4][64][64];  // [t][h], chunk-swizzled, 4-buffer rotation
  __shared__ u16 Vs[4][64][64];  // [h][t], chunk-swizzled

  bf16x8 qf[4];
#pragma unroll
  for (int kf = 0; kf < 4; ++kf)
    qf[kf] = *(const bf16x8*)(qtb + (size_t)f * 64 + kf * 16 + g * 8);

  f32x16 ctx[2];
#pragma unroll
  for (int m = 0; m < 2; ++m)
#pragma unroll
    for (int r = 0; r < 16; ++r) ctx[m][r] = 0.f;
  float L = 0.f;

  // staging geometry: wave w owns rows w*16..w*16+15 (2 gload_lds per tensor)
  const int sr1 = w * 16 + (lane >> 3), sr2 = sr1 + 8;
  const int sc1 = (lane & 7) ^ (sr1 & 7), sc2 = (lane & 7) ^ (sr2 & 7);
  const u16* ksrc1 = ktb + (size_t)sr1 * 64 + sc1 * 8;
  const u16* ksrc2 = ktb + (size_t)sr2 * 64 + sc2 * 8;
  const u16* vsrc1 = vb + (size_t)sr1 * 2048 + sc1 * 8;
  const u16* vsrc2 = vb + (size_t)sr2 * 2048 + sc2 * 8;

  bf16x8 kreg[2][4], vreg[2][4];
  f32x16 sA[2], sB[2];

  // ---- prologue: stage tiles 0,1; compute QK_0 into sA ----
  STAGE(0, 0);
  STAGE(1, 64);
  SB;
  asm volatile("s_waitcnt vmcnt(0)" ::: "memory");
  SB;
  __builtin_amdgcn_s_barrier();
  SB;
  LDK(0);
  QKMM(sA);  // s_0 (compiler inserts precise lgkm waits)

  for (int t0 = 0; t0 < 2048; t0 += 256) {
    ROUND(0, sA, sB, t0);
    ROUND(1, sB, sA, t0 + 64);
    ROUND(2, sA, sB, t0 + 128);
    ROUND(3, sB, sA, t0 + 192);
  }

  const float Linv = 1.0f / L;
#pragma unroll
  for (int mih = 0; mih < 2; ++mih)
#pragma unroll
    for (int r = 0; r < 16; ++r) {
      const int h = mih * 32 + (r & 3) + 8 * (r >> 2) + 4 * g;
      out[((size_t)b * 512 + n * 64 + h) * 2048 + f] = ctx[mih][r] * Linv;
    }
}

extern "C" void kernel_launch(void* const* d_in, const int* in_sizes, int n_in,
                              void* d_out, int out_size, void* d_ws, size_t ws_size,
                              hipStream_t stream) {
  const float* from_t = (const float*)d_in[0];
  const float* to_t   = (const float*)d_in[1];
  const float* mask   = (const float*)d_in[2];
  const float* Wq     = (const float*)d_in[3];
  const float* bq     = (const float*)d_in[4];
  const float* Wk     = (const float*)d_in[5];
  const float* bk     = (const float*)d_in[6];
  const float* Wv     = (const float*)d_in[7];
  const float* bv     = (const float*)d_in[8];
  float* out = (float*)d_out;

  u16* qt = (u16*)d_ws;                        // [4][8][2048][64] bf16 = 8MB
  u16* kt = qt + (size_t)4 * 8 * 2048 * 64;    // 8MB
  u16* vt = kt + (size_t)4 * 8 * 2048 * 64;    // [4][512][2048] bf16 = 8MB
  const size_t base = (size_t)24 * 1024 * 1024;
  u32* fl = (ws_size >= base + 256) ? (u32*)((char*)d_ws + base) : nullptr;

  proj_kernel<<<dim3(768), 512, 0, stream>>>(from_t, to_t, Wq, bq, Wk, bk,
                                             Wv, bv, qt, kt, vt);
  if (fl) {
    (void)hipMemsetAsync(fl, 0, 64 * sizeof(u32), stream);
    maskflag_kernel<<<dim3(2048), 256, 0, stream>>>(mask, fl);
  }
  attn_kernel<<<dim3(512), 256, 0, stream>>>(mask, fl, qt, kt, vt, out);
}